// Round 1
// baseline (370.027 us; speedup 1.0000x reference)
//
#include <hip/hip_runtime.h>
#include <math.h>

#define BB 64
#define NN 8192
#define MM 128
#define HH 512
#define KLSTM 896   // 384 (x|pr) + 512 (h0)
#define JTOT 2048
#define COLS 658    // 134 (ro0) + 390 (wo0) + 134 (ro1)
#define OUTN 128
#define CHUNKS 32   // 8192/32 = 256 rows per chunk

__device__ __forceinline__ float sigmoidf_(float x){ return 1.0f/(1.0f+expf(-x)); }
__device__ __forceinline__ float softplusf_(float x){ return (x>20.0f)? x : log1pf(expf(x)); }

// ---------- 1. inp896 = [x | pr0 | pr1 | h0] ----------
__global__ void k_build_inp(const float* __restrict__ x, const float* __restrict__ pr,
                            const float* __restrict__ h0, float* __restrict__ inp)
{
  int idx = blockIdx.x*256 + threadIdx.x;
  if (idx >= BB*KLSTM) return;
  int b = idx / KLSTM, k = idx % KLSTM;
  float v;
  if (k < 128)      v = x[b*128 + k];
  else if (k < 256) v = pr[0*BB*MM + b*MM + (k-128)];
  else if (k < 384) v = pr[1*BB*MM + b*MM + (k-256)];
  else              v = h0[b*HH + (k-384)];
  inp[idx] = v;
}

// ---------- 2. LSTM gemm: gates[b][j] = sum_k inp[b][k]*Wcat[j][k] + biases ----------
__global__ __launch_bounds__(1024) void k_lstm_gemm(
    const float* __restrict__ inp, const float* __restrict__ Wih,
    const float* __restrict__ Whh, const float* __restrict__ bih,
    const float* __restrict__ bhh, float* __restrict__ gates)
{
  __shared__ float inp_s[64*65];   // [k][b]
  __shared__ float w_s[64*68];     // [k][j]
  int tid = threadIdx.x;
  int b = tid & 63, jl = tid >> 6;      // jl in 0..15, owns 4 consecutive j
  int jbase = blockIdx.x*64;
  float ax=0.f, ay=0.f, az=0.f, aw=0.f;
  for (int kc=0; kc<KLSTM; kc+=64){
    #pragma unroll
    for (int i=0;i<4;i++){
      int idx = tid + i*1024;
      int kk = idx & 63, p = idx >> 6;
      inp_s[kk*65+p] = inp[p*KLSTM + kc + kk];
      int kglob = kc + kk;
      float wv = (kglob < 384) ? Wih[(size_t)(jbase+p)*384 + kglob]
                               : Whh[(size_t)(jbase+p)*512 + (kglob-384)];
      w_s[kk*68 + p] = wv;
    }
    __syncthreads();
    #pragma unroll 8
    for (int kk=0; kk<64; ++kk){
      float a = inp_s[kk*65 + b];
      const float4 w4 = *(const float4*)&w_s[kk*68 + jl*4];
      ax += a*w4.x; ay += a*w4.y; az += a*w4.z; aw += a*w4.w;
    }
    __syncthreads();
  }
  int j0 = jbase + jl*4;
  float4 o;
  o.x = ax + bih[j0+0] + bhh[j0+0];
  o.y = ay + bih[j0+1] + bhh[j0+1];
  o.z = az + bih[j0+2] + bhh[j0+2];
  o.w = aw + bih[j0+3] + bhh[j0+3];
  *(float4*)&gates[(size_t)b*JTOT + j0] = o;
}

// ---------- 3. LSTM activations ----------
__global__ void k_lstm_act(const float* __restrict__ gates, const float* __restrict__ c0,
                           float* __restrict__ ctrl)
{
  int idx = blockIdx.x*256 + threadIdx.x;
  if (idx >= BB*HH) return;
  int b = idx / HH, h = idx % HH;
  const float* g = gates + (size_t)b*JTOT;
  float i_ = sigmoidf_(g[h]);
  float f_ = sigmoidf_(g[HH + h]);
  float gg = tanhf(g[2*HH + h]);
  float o_ = sigmoidf_(g[3*HH + h]);
  float cn = f_*c0[idx] + i_*gg;
  ctrl[idx] = o_*tanhf(cn);
}

// ---------- 4. head gemm: roall[b][col] = ctrl[b]·W[col] + bias, col<658 ----------
__global__ __launch_bounds__(1024) void k_head_gemm(
    const float* __restrict__ ctrl, const float* __restrict__ Wr,
    const float* __restrict__ br, const float* __restrict__ Ww,
    const float* __restrict__ bw, float* __restrict__ roall)
{
  __shared__ float c_s[64*65];   // [k][b]
  __shared__ float w_s[64*68];   // [k][col]
  int tid = threadIdx.x;
  int b = tid & 63, cl = tid >> 6;
  int cbase = blockIdx.x*64;
  float ac[4] = {0.f,0.f,0.f,0.f};
  for (int kc=0; kc<HH; kc+=64){
    #pragma unroll
    for (int i=0;i<4;i++){
      int idx = tid + i*1024;
      int kk = idx & 63, p = idx >> 6;
      c_s[kk*65+p] = ctrl[(size_t)p*HH + kc + kk];
      int col = cbase + p;
      float wv = 0.0f;
      if (col < 134)      wv = Wr[(size_t)col*HH + kc + kk];
      else if (col < 524) wv = Ww[(size_t)(col-134)*HH + kc + kk];
      else if (col < COLS) wv = Wr[(size_t)(134 + col-524)*HH + kc + kk];
      w_s[kk*68 + p] = wv;
    }
    __syncthreads();
    #pragma unroll 8
    for (int kk=0; kk<64; ++kk){
      float a = c_s[kk*65 + b];
      const float4 w4 = *(const float4*)&w_s[kk*68 + cl*4];
      ac[0] += a*w4.x; ac[1] += a*w4.y; ac[2] += a*w4.z; ac[3] += a*w4.w;
    }
    __syncthreads();
  }
  #pragma unroll
  for (int t=0;t<4;t++){
    int col = cbase + cl*4 + t;
    if (col < COLS){
      float bias = (col<134)? br[col] : (col<524)? bw[col-134] : br[134 + col-524];
      roall[(size_t)b*COLS + col] = ac[t] + bias;
    }
  }
}

// ---------- 5. param extraction ----------
// roall layout: [ro0: 0..133 | wo0: 134..523 | ro1: 524..657]
__global__ void k_params(const float* __restrict__ roall,
                         float* __restrict__ kr0, float* __restrict__ kw0,
                         float* __restrict__ kr1, float* __restrict__ e0,
                         float* __restrict__ a0, float* __restrict__ scal)
{
  int b = blockIdx.x;
  int m = threadIdx.x;   // 128
  const float* ro = roall + (size_t)b*COLS;
  kr0[b*MM+m] = ro[m];
  kw0[b*MM+m] = ro[134 + m];
  kr1[b*MM+m] = ro[524 + m];
  e0 [b*MM+m] = sigmoidf_(ro[268 + m]);  // wo cols 134..261
  a0 [b*MM+m] = ro[396 + m];             // wo cols 262..389
  if (m < 3){
    int base = (m==0)? 0 : (m==1)? 134 : 524;
    float beta  = softplusf_(ro[base+128]);
    float g     = sigmoidf_(ro[base+129]);
    float s0r = ro[base+130], s1r = ro[base+131], s2r = ro[base+132];
    float mx = fmaxf(s0r, fmaxf(s1r, s2r));
    float es0 = expf(s0r-mx), es1 = expf(s1r-mx), es2 = expf(s2r-mx);
    float es = es0+es1+es2;
    float gamma = 1.0f + softplusf_(ro[base+133]);
    float ss = 0.f;
    for (int t=0;t<MM;t++){ float kv = ro[base+t]; ss += kv*kv; }
    float kn = fmaxf(sqrtf(ss), 1e-8f);
    float* sc = scal + ((size_t)m*BB + b)*7;
    sc[0]=beta; sc[1]=g; sc[2]=es0/es; sc[3]=es1/es; sc[4]=es2/es; sc[5]=gamma; sc[6]=kn;
  }
}

// ---------- 6. pass A: mem0 dots with k_r0, k_w0 + row norms ----------
__global__ __launch_bounds__(256) void k_passA(
    const float* __restrict__ mem, const float* __restrict__ kr0,
    const float* __restrict__ kw0, float* __restrict__ num_r0,
    float* __restrict__ num_w0, float* __restrict__ norm0)
{
  int b = blockIdx.y, chunk = blockIdx.x;
  int tid = threadIdx.x, ty = tid>>5, lane = tid&31;
  float4 kr = ((const float4*)(kr0 + (size_t)b*MM))[lane];
  float4 kw = ((const float4*)(kw0 + (size_t)b*MM))[lane];
  for (int it=0; it<32; ++it){
    int n = chunk*256 + it*8 + ty;
    const float4* row = (const float4*)(mem + ((size_t)b*NN + n)*MM);
    float4 v = row[lane];
    float sr = v.x*kr.x + v.y*kr.y + v.z*kr.z + v.w*kr.w;
    float sw = v.x*kw.x + v.y*kw.y + v.z*kw.z + v.w*kw.w;
    float ss = v.x*v.x + v.y*v.y + v.z*v.z + v.w*v.w;
    #pragma unroll
    for (int off=16; off; off>>=1){
      sr += __shfl_xor(sr, off);
      sw += __shfl_xor(sw, off);
      ss += __shfl_xor(ss, off);
    }
    if (lane==0){
      size_t p = (size_t)b*NN + n;
      num_r0[p] = sr; num_w0[p] = sw; norm0[p] = sqrtf(ss);
    }
  }
}

// ---------- 7. addressing: softmax -> interpolate -> shift -> sharpen ----------
__global__ __launch_bounds__(256) void k_addr(
    const float* __restrict__ num, const float* __restrict__ normv,
    const float* __restrict__ scal, const float* __restrict__ wprevA,
    const float* __restrict__ wprevB, float* __restrict__ wout, int roleBase)
{
  int b = blockIdx.x, which = blockIdx.y;
  const float* numb  = num + (size_t)which*BB*NN + (size_t)b*NN;
  const float* nb    = normv + (size_t)b*NN;
  const float* wprev = ((which==0)? wprevA : wprevB) + (size_t)b*NN;
  float* wo = wout + (size_t)which*BB*NN + (size_t)b*NN;
  const float* sc = scal + ((size_t)(roleBase+which)*BB + b)*7;
  float beta=sc[0], g=sc[1], s0=sc[2], s1=sc[3], s2=sc[4], gamma=sc[5], kn=sc[6];

  __shared__ float buf[NN];
  __shared__ float red[256];
  int tid = threadIdx.x;

  // logits + max
  float lmax = -1e30f;
  for (int n=tid; n<NN; n+=256){
    float den = fmaxf(nb[n], 1e-8f) * kn;
    float l = beta * numb[n] / den;
    buf[n] = l;
    lmax = fmaxf(lmax, l);
  }
  red[tid] = lmax; __syncthreads();
  for (int s=128; s>0; s>>=1){ if (tid<s) red[tid]=fmaxf(red[tid],red[tid+s]); __syncthreads(); }
  lmax = red[0]; __syncthreads();
  // exp + sum
  float lsum = 0.f;
  for (int n=tid; n<NN; n+=256){ float e = expf(buf[n]-lmax); buf[n]=e; lsum+=e; }
  red[tid] = lsum; __syncthreads();
  for (int s=128; s>0; s>>=1){ if (tid<s) red[tid]+=red[tid+s]; __syncthreads(); }
  float inv = 1.0f/red[0]; __syncthreads();
  // wg = g*wc + (1-g)*wprev
  for (int n=tid; n<NN; n+=256){ float wc = buf[n]*inv; buf[n] = g*wc + (1.0f-g)*wprev[n]; }
  __syncthreads();
  // shift + sharpen
  float wt_loc[32];
  float psum = 0.f;
  #pragma unroll
  for (int i=0;i<32;i++){
    int n = tid + i*256;
    float wm = buf[(n-1)&(NN-1)];
    float w0 = buf[n];
    float wp = buf[(n+1)&(NN-1)];
    float wt = s0*wm + s1*w0 + s2*wp;
    float p = powf(wt, gamma);
    wt_loc[i] = p; psum += p;
  }
  red[tid] = psum; __syncthreads();
  for (int s=128; s>0; s>>=1){ if (tid<s) red[tid]+=red[tid+s]; __syncthreads(); }
  float invp = 1.0f/(red[0] + 1e-16f);
  #pragma unroll
  for (int i=0;i<32;i++) wo[tid + i*256] = wt_loc[i]*invp;
}

// ---------- 8. pass B: read0 partials + mem1 dots (mem1 computed on the fly) ----------
__global__ __launch_bounds__(256) void k_passB(
    const float* __restrict__ mem, const float* __restrict__ wr0,
    const float* __restrict__ ww0, const float* __restrict__ e0,
    const float* __restrict__ a0, const float* __restrict__ kr1,
    float* __restrict__ partA, float* __restrict__ num_r1, float* __restrict__ norm1)
{
  int b = blockIdx.y, chunk = blockIdx.x;
  int tid = threadIdx.x, ty = tid>>5, lane = tid&31;
  float4 e4 = ((const float4*)(e0 + (size_t)b*MM))[lane];
  float4 a4 = ((const float4*)(a0 + (size_t)b*MM))[lane];
  float4 k4 = ((const float4*)(kr1 + (size_t)b*MM))[lane];
  float4 acc = {0.f,0.f,0.f,0.f};
  for (int it=0; it<32; ++it){
    int n = chunk*256 + it*8 + ty;
    size_t p = (size_t)b*NN + n;
    const float4* row = (const float4*)(mem + p*MM);
    float4 v = row[lane];
    float wr = wr0[p], ww = ww0[p];
    acc.x += wr*v.x; acc.y += wr*v.y; acc.z += wr*v.z; acc.w += wr*v.w;
    float4 v1;
    v1.x = v.x*(1.f - ww*e4.x) + ww*a4.x;
    v1.y = v.y*(1.f - ww*e4.y) + ww*a4.y;
    v1.z = v.z*(1.f - ww*e4.z) + ww*a4.z;
    v1.w = v.w*(1.f - ww*e4.w) + ww*a4.w;
    float sr = v1.x*k4.x + v1.y*k4.y + v1.z*k4.z + v1.w*k4.w;
    float ss = v1.x*v1.x + v1.y*v1.y + v1.z*v1.z + v1.w*v1.w;
    #pragma unroll
    for (int off=16; off; off>>=1){
      sr += __shfl_xor(sr, off);
      ss += __shfl_xor(ss, off);
    }
    if (lane==0){ num_r1[p] = sr; norm1[p] = sqrtf(ss); }
  }
  __shared__ float4 sred[256];
  sred[tid] = acc;
  __syncthreads();
  if (ty == 0){
    float4 s = {0.f,0.f,0.f,0.f};
    #pragma unroll
    for (int r=0;r<8;r++){
      float4 t = sred[r*32 + lane];
      s.x += t.x; s.y += t.y; s.z += t.z; s.w += t.w;
    }
    ((float4*)(partA + ((size_t)(b*CHUNKS + chunk))*MM))[lane] = s;
  }
}

// ---------- 9. pass C: read1 partials from recomputed mem1 ----------
__global__ __launch_bounds__(256) void k_passC(
    const float* __restrict__ mem, const float* __restrict__ wr1,
    const float* __restrict__ ww0, const float* __restrict__ e0,
    const float* __restrict__ a0, float* __restrict__ partB)
{
  int b = blockIdx.y, chunk = blockIdx.x;
  int tid = threadIdx.x, ty = tid>>5, lane = tid&31;
  float4 e4 = ((const float4*)(e0 + (size_t)b*MM))[lane];
  float4 a4 = ((const float4*)(a0 + (size_t)b*MM))[lane];
  float4 acc = {0.f,0.f,0.f,0.f};
  for (int it=0; it<32; ++it){
    int n = chunk*256 + it*8 + ty;
    size_t p = (size_t)b*NN + n;
    const float4* row = (const float4*)(mem + p*MM);
    float4 v = row[lane];
    float wr = wr1[p], ww = ww0[p];
    float4 v1;
    v1.x = v.x*(1.f - ww*e4.x) + ww*a4.x;
    v1.y = v.y*(1.f - ww*e4.y) + ww*a4.y;
    v1.z = v.z*(1.f - ww*e4.z) + ww*a4.z;
    v1.w = v.w*(1.f - ww*e4.w) + ww*a4.w;
    acc.x += wr*v1.x; acc.y += wr*v1.y; acc.z += wr*v1.z; acc.w += wr*v1.w;
  }
  __shared__ float4 sred[256];
  sred[tid] = acc;
  __syncthreads();
  if (ty == 0){
    float4 s = {0.f,0.f,0.f,0.f};
    #pragma unroll
    for (int r=0;r<8;r++){
      float4 t = sred[r*32 + lane];
      s.x += t.x; s.y += t.y; s.z += t.z; s.w += t.w;
    }
    ((float4*)(partB + ((size_t)(b*CHUNKS + chunk))*MM))[lane] = s;
  }
}

// ---------- 10. reduce partials -> inp2T[k][b] ----------
__global__ void k_reduce(const float* __restrict__ pA, const float* __restrict__ pB,
                         float* __restrict__ inp2T)
{
  int b = blockIdx.x; int m = threadIdx.x;   // 128
  float sA=0.f, sB=0.f;
  for (int c=0;c<CHUNKS;c++){
    sA += pA[((size_t)(b*CHUNKS + c))*MM + m];
    sB += pB[((size_t)(b*CHUNKS + c))*MM + m];
  }
  inp2T[(size_t)m*BB + b] = sA;
  inp2T[(size_t)(MM+m)*BB + b] = sB;
}

// ---------- 11. fc + sigmoid ----------
__global__ void k_fc(const float* __restrict__ inp2T, const float* __restrict__ fcW,
                     const float* __restrict__ fcb, float* __restrict__ out)
{
  int tid = threadIdx.x;
  int b = tid & 63, ol = tid >> 6;       // 4 o per block
  int o = blockIdx.x*4 + ol;
  float acc = fcb[o];
  #pragma unroll 4
  for (int k=0;k<2*MM;k++){
    acc += fcW[(size_t)o*(2*MM) + k] * inp2T[(size_t)k*BB + b];
  }
  out[(size_t)b*OUTN + o] = sigmoidf_(acc);
}

extern "C" void kernel_launch(void* const* d_in, const int* in_sizes, int n_in,
                              void* d_out, int out_size, void* d_ws, size_t ws_size,
                              hipStream_t stream) {
  const float* x   = (const float*)d_in[0];
  const float* pr  = (const float*)d_in[1];
  const float* h0  = (const float*)d_in[2];
  const float* c0  = (const float*)d_in[3];
  const float* pwr = (const float*)d_in[4];
  const float* pww = (const float*)d_in[5];
  const float* mem = (const float*)d_in[6];
  const float* Wih = (const float*)d_in[7];
  const float* Whh = (const float*)d_in[8];
  const float* bih = (const float*)d_in[9];
  const float* bhh = (const float*)d_in[10];
  const float* Wr  = (const float*)d_in[11];
  const float* br  = (const float*)d_in[12];
  const float* Ww  = (const float*)d_in[13];
  const float* bw  = (const float*)d_in[14];
  const float* fcW = (const float*)d_in[15];
  const float* fcb = (const float*)d_in[16];
  float* out = (float*)d_out;

  float* ws = (float*)d_ws;
  size_t off = 0;
  auto alloc = [&](size_t n){ float* p = ws + off; off += n; return p; };
  float* INP   = alloc((size_t)BB*KLSTM);
  float* GATES = alloc((size_t)BB*JTOT);
  float* CTRL  = alloc((size_t)BB*HH);
  float* ROALL = alloc((size_t)BB*COLS);
  float* KR0   = alloc((size_t)BB*MM);
  float* KW0   = alloc((size_t)BB*MM);
  float* KR1   = alloc((size_t)BB*MM);
  float* E0    = alloc((size_t)BB*MM);
  float* A0    = alloc((size_t)BB*MM);
  float* SCAL  = alloc((size_t)3*BB*7 + 4);
  float* NUMR0 = alloc((size_t)BB*NN);
  float* NUMW0 = alloc((size_t)BB*NN);   // must stay adjacent to NUMR0
  float* NORM0 = alloc((size_t)BB*NN);
  float* NUMR1 = alloc((size_t)BB*NN);
  float* NORM1 = alloc((size_t)BB*NN);
  float* WR0   = alloc((size_t)BB*NN);
  float* WW0   = alloc((size_t)BB*NN);   // must stay adjacent to WR0
  float* WR1   = alloc((size_t)BB*NN);
  float* PARTA = alloc((size_t)BB*CHUNKS*MM);
  float* PARTB = alloc((size_t)BB*CHUNKS*MM);
  float* INP2T = alloc((size_t)2*MM*BB);
  (void)ws_size; (void)in_sizes; (void)n_in; (void)out_size;
  (void)NUMW0; (void)WW0;

  k_build_inp<<<(BB*KLSTM+255)/256, 256, 0, stream>>>(x, pr, h0, INP);
  k_lstm_gemm<<<JTOT/64, 1024, 0, stream>>>(INP, Wih, Whh, bih, bhh, GATES);
  k_lstm_act<<<(BB*HH+255)/256, 256, 0, stream>>>(GATES, c0, CTRL);
  k_head_gemm<<<(COLS+63)/64, 1024, 0, stream>>>(CTRL, Wr, br, Ww, bw, ROALL);
  k_params<<<BB, 128, 0, stream>>>(ROALL, KR0, KW0, KR1, E0, A0, SCAL);
  k_passA<<<dim3(CHUNKS,BB), 256, 0, stream>>>(mem, KR0, KW0, NUMR0, NUMW0, NORM0);
  k_addr<<<dim3(BB,2), 256, 0, stream>>>(NUMR0, NORM0, SCAL, pwr, pww, WR0, 0);
  k_passB<<<dim3(CHUNKS,BB), 256, 0, stream>>>(mem, WR0, WW0, E0, A0, KR1, PARTA, NUMR1, NORM1);
  k_addr<<<dim3(BB,1), 256, 0, stream>>>(NUMR1, NORM1, SCAL, pwr + (size_t)BB*NN, pww, WR1, 2);
  k_passC<<<dim3(CHUNKS,BB), 256, 0, stream>>>(mem, WR1, WW0, E0, A0, PARTB);
  k_reduce<<<BB, 128, 0, stream>>>(PARTA, PARTB, INP2T);
  k_fc<<<OUTN/4, 256, 0, stream>>>(INP2T, fcW, fcb, out);
}